// Round 6
// baseline (41.555 us; speedup 1.0000x reference)
//
#include <hip/hip_runtime.h>
#include <hip/hip_bf16.h>

typedef __attribute__((ext_vector_type(8))) short short8;
typedef __attribute__((ext_vector_type(8))) unsigned short ushort8;
typedef __attribute__((ext_vector_type(16))) float f32x16;

#define LOG2E 1.4426950408889634f
#define MFMA32(a, b, c) __builtin_amdgcn_mfma_f32_32x32x16_bf16((a), (b), (c), 0, 0, 0)
#define ZERO16 {0.f,0.f,0.f,0.f,0.f,0.f,0.f,0.f,0.f,0.f,0.f,0.f,0.f,0.f,0.f,0.f}

__device__ __forceinline__ unsigned short bfbits(float f) {
    __hip_bfloat16 h = __float2bfloat16(f);
    return __builtin_bit_cast(unsigned short, h);
}
__device__ __forceinline__ float bf2f(unsigned short u) {
    unsigned v = ((unsigned)u) << 16;
    return __builtin_bit_cast(float, v);
}

typedef unsigned int __attribute__((address_space(1))) as1_u32;
typedef unsigned int __attribute__((address_space(3))) as3_u32;
__device__ __forceinline__ void gload_lds16(const void* g, void* l) {
    __builtin_amdgcn_global_load_lds((const as1_u32*)g, (as3_u32*)l, 16, 0, 0);
}

// ---- kernel 0: W[k][d] -> WT2[k/16][d][k%16] bf16 hi/lo; init f2m keys ---------
__global__ __launch_bounds__(256) void gat_wt(const float* __restrict__ W,
                                              unsigned short* __restrict__ WT2h,
                                              unsigned short* __restrict__ WT2l,
                                              unsigned int* __restrict__ f2mk) {
    if (blockIdx.x == 0 && threadIdx.x < 8) f2mk[threadIdx.x] = 0u;
    const int k16 = blockIdx.x;            // 8 tiles of 16 k
    const int d = threadIdx.x >> 1;
    const int klo8 = (threadIdx.x & 1) * 8;
    ushort8 vh, vl;
#pragma unroll
    for (int q = 0; q < 8; ++q) {
        float f = W[(k16 * 16 + klo8 + q) * 128 + d];
        unsigned short hb = bfbits(f);
        vh[q] = hb;
        vl[q] = bfbits(f - bf2f(hb));
    }
    size_t base = (size_t)k16 * 2048 + d * 16 + klo8;
    *(ushort8*)(WT2h + base) = vh;
    *(ushort8*)(WT2l + base) = vl;
}

// ---- kernel 1: h = x@W via MFMA (hi/lo); writes HT2[j/16][d][j%16], f1l, f2l,
//                and per-batch f2 max via atomicMax on sign-flipped uint key ----
__global__ __launch_bounds__(256) void gat_h(const float* __restrict__ x,
                                             const unsigned short* __restrict__ WT2h,
                                             const unsigned short* __restrict__ WT2l,
                                             const float* __restrict__ a,
                                             unsigned short* __restrict__ HT2h,
                                             float* __restrict__ f1l,
                                             float* __restrict__ f2l,
                                             unsigned int* __restrict__ f2mk) {
    __shared__ unsigned short xs_h[32][132];
    __shared__ unsigned short xs_l[32][132];
    __shared__ float hs[32][130];
    __shared__ float red[2][32][8];
    const int tid = threadIdx.x;
    const int lane = tid & 63;
    const int wv = tid >> 6;          // 4 waves, one 32-col tile each
    const int l31 = lane & 31;
    const int hi = lane >> 5;
    const int t0 = blockIdx.x * 32;   // global row (8*2048 rows total)
    const int c0 = wv * 32;

    // stage x tile coalesced, convert to bf16 hi/lo once
#pragma unroll
    for (int r8 = 0; r8 < 4; ++r8) {
        int row = r8 * 8 + (tid >> 5);
        int c4 = (tid & 31) * 4;
        float4 v = *(const float4*)(x + (size_t)(t0 + row) * 128 + c4);
        float f[4] = {v.x, v.y, v.z, v.w};
#pragma unroll
        for (int q = 0; q < 4; ++q) {
            unsigned short hb = bfbits(f[q]);
            xs_h[row][c4 + q] = hb;
            xs_l[row][c4 + q] = bfbits(f[q] - bf2f(hb));
        }
    }
    __syncthreads();

    f32x16 p0 = ZERO16, p1 = ZERO16, p2 = ZERO16;  // xhi*Whi, xlo*Whi, xhi*Wlo
    const unsigned short* bph = WT2h + (c0 + l31) * 16 + 8 * hi;
    const unsigned short* bpl = WT2l + (c0 + l31) * 16 + 8 * hi;
#pragma unroll
    for (int kk8 = 0; kk8 < 8; ++kk8) {
        short8 ah = *(const short8*)&xs_h[l31][kk8 * 16 + 8 * hi];
        short8 al = *(const short8*)&xs_l[l31][kk8 * 16 + 8 * hi];
        short8 bh = __builtin_bit_cast(short8, *(const ushort8*)(bph + kk8 * 2048));
        short8 bl = __builtin_bit_cast(short8, *(const ushort8*)(bpl + kk8 * 2048));
        p0 = MFMA32(ah, bh, p0);
        p1 = MFMA32(al, bh, p1);
        p2 = MFMA32(ah, bl, p2);
    }
#pragma unroll
    for (int r = 0; r < 16; ++r) {
        int crow = (r & 3) + 8 * (r >> 2) + 4 * hi;
        hs[crow][c0 + l31] = p0[r] + p1[r] + p2[r];
    }
    __syncthreads();
    // HT2 writes: thread owns one d, 16 consecutive j's -> contiguous 32B
    {
        const int d = tid & 127, half = tid >> 7;
        ushort8 h0, h1;
#pragma unroll
        for (int j = 0; j < 8; ++j) h0[j] = bfbits(hs[half * 16 + j][d]);
#pragma unroll
        for (int j = 0; j < 8; ++j) h1[j] = bfbits(hs[half * 16 + 8 + j][d]);
        const int b = t0 >> 11;
        const int tloc = t0 & 2047;
        size_t base = (size_t)b * 262144 + (size_t)(tloc / 16 + half) * 2048 + d * 16;
        *(ushort8*)(HT2h + base) = h0;
        *(ushort8*)(HT2h + base + 8) = h1;
    }
    // f1 = h@a1, f2 = h@a2 (pre-scaled by log2e)
    {
        const int r = tid & 31, seg = tid >> 5;
        float s1 = 0.f, s2 = 0.f;
#pragma unroll
        for (int i = 0; i < 16; ++i) {
            float hv = hs[r][seg * 16 + i];
            s1 += hv * a[seg * 16 + i];
            s2 += hv * a[128 + seg * 16 + i];
        }
        red[0][r][seg] = s1;
        red[1][r][seg] = s2;
    }
    __syncthreads();
    if (tid < 32) {
        float s1 = 0.f, s2 = 0.f;
#pragma unroll
        for (int g = 0; g < 8; ++g) { s1 += red[0][tid][g]; s2 += red[1][tid][g]; }
        f1l[t0 + tid] = s1 * LOG2E;
        float f2v = s2 * LOG2E;
        f2l[t0 + tid] = f2v;
        // block-level f2 max -> one atomicMax per block (sign-flipped uint key)
        float m = f2v;
#pragma unroll
        for (int o = 1; o < 32; o <<= 1) m = fmaxf(m, __shfl_xor(m, o, 32));
        if (tid == 0) {
            unsigned int bits = __builtin_bit_cast(unsigned int, m);
            unsigned int key = (bits & 0x80000000u) ? ~bits : (bits | 0x80000000u);
            atomicMax(f2mk + (t0 >> 11), key);
        }
    }
}

// ---- helper: generate af fragments + accumulate softmax partials ---------------
__device__ __forceinline__ void gen_af(float4 fa, float4 fb,
                                       float A0, float B0, float A1, float B1,
                                       float& sp0, float& sp1,
                                       short8& af0, short8& af1) {
    float fv[8] = {fa.x, fa.y, fa.z, fa.w, fb.x, fb.y, fb.z, fb.w};
#pragma unroll
    for (int q = 0; q < 8; ++q) {
        float g = 0.2f * fv[q];
        float p0 = __builtin_amdgcn_exp2f(fmaxf(A0 + fv[q], B0 + g));
        float p1 = __builtin_amdgcn_exp2f(fmaxf(A1 + fv[q], B1 + g));
        sp0 += p0; sp1 += p1;
        af0[q] = (short)bfbits(p0);
        af1[q] = (short)bfbits(p1);
    }
}

// ---- kernel 2: fused P-gen + softmax-denominator + P@H -------------------------
// 512 threads = 8 waves, each wave: 64 rows x ALL 128 d x one 256-j chunk.
// H staged via per-wave global_load_lds DMA pipeline (depth 4, zero VGPR cost),
// counted vmcnt(12) waits; staging LDS barrier-aliased with epilogue lred.
__global__ __launch_bounds__(512, 2) void gat_attn(const unsigned short* __restrict__ HT2h,
                                                   const float* __restrict__ f1l,
                                                   const float* __restrict__ f2l,
                                                   const unsigned int* __restrict__ f2mk,
                                                   float* __restrict__ out) {
    __shared__ __align__(16) unsigned char smem[131072]; // loop: DMA staging / epi: lred
    __shared__ float f2s[2048];
    __shared__ float sps[8][64];
    __shared__ float sinv[64];
    const int bid = blockIdx.x;
    const int b = bid & 7;          // batch == XCD for L2 locality
    const int tile = bid >> 3;      // 0..31, 64 rows each
    const int tid = threadIdx.x;
    const int lane = tid & 63;
    const int wv = tid >> 6;        // 0..7 = j-chunk
    const int l31 = lane & 31;
    const int hi = lane >> 5;
    const int koff = hi * 8;

    // stage f2 batch slice into LDS (one coalesced burst)
    *(float4*)(f2s + tid * 4) = *(const float4*)(f2l + b * 2048 + tid * 4);

    const unsigned int kk = f2mk[b];
    const unsigned int mbits = (kk & 0x80000000u) ? (kk & 0x7fffffffu) : ~kk;
    const float fm = __builtin_bit_cast(float, mbits);

    const int rowg = b * 2048 + tile * 64 + l31;
    const float f1m0 = f1l[rowg];
    const float f1m1 = f1l[rowg + 32];
    const float tm0 = f1m0 + fm, tm1 = f1m1 + fm;
    const float ml0 = fmaxf(tm0, 0.2f * tm0);    // exact row max (lrelu monotonic)
    const float ml1 = fmaxf(tm1, 0.2f * tm1);
    const float A0 = f1m0 - ml0, B0 = 0.2f * f1m0 - ml0;
    const float A1 = f1m1 - ml1, B1 = 0.2f * f1m1 - ml1;

    const int jloc = wv * 256;
    // per-lane global source of this wave's B-fragments
    const unsigned short* gbase = HT2h + (size_t)b * 262144 + (size_t)(jloc >> 4) * 2048
                                + l31 * 16 + koff;
    // wave-uniform LDS staging base (HW adds lane*16B)
    unsigned short* sbase = (unsigned short*)smem + wv * 8192;

    __syncthreads();   // f2s ready; drains all prior vmem (clean vmcnt base)

    // prologue: DMA groups 0..3 (16 loads outstanding)
#pragma unroll
    for (int g = 0; g < 4; ++g) {
#pragma unroll
        for (int c = 0; c < 4; ++c)
            gload_lds16(gbase + (size_t)g * 2048 + c * 512, sbase + g * 2048 + c * 512);
    }

    f32x16 acc[2][4] = {{ZERO16, ZERO16, ZERO16, ZERO16},
                        {ZERO16, ZERO16, ZERO16, ZERO16}};
    float sp0 = 0.f, sp1 = 0.f;

    for (int i = 0; i < 16; ++i) {
        // counted wait: oldest group (4 loads) complete, 12 newer stay in flight
        asm volatile("s_waitcnt vmcnt(12)" ::: "memory");
        __builtin_amdgcn_sched_barrier(0);
        const unsigned short* rp = sbase + (i & 3) * 2048 + lane * 8;
        uint4 v0 = *(const uint4*)(rp);
        uint4 v1 = *(const uint4*)(rp + 512);
        uint4 v2 = *(const uint4*)(rp + 1024);
        uint4 v3 = *(const uint4*)(rp + 1536);
        float4 fa = *(const float4*)(f2s + jloc + i * 16 + koff);
        float4 fb = *(const float4*)(f2s + jloc + i * 16 + koff + 4);
        short8 af0, af1;
        gen_af(fa, fb, A0, B0, A1, B1, sp0, sp1, af0, af1);
        acc[0][0] = MFMA32(af0, __builtin_bit_cast(short8, v0), acc[0][0]);
        acc[0][1] = MFMA32(af0, __builtin_bit_cast(short8, v1), acc[0][1]);
        acc[0][2] = MFMA32(af0, __builtin_bit_cast(short8, v2), acc[0][2]);
        acc[0][3] = MFMA32(af0, __builtin_bit_cast(short8, v3), acc[0][3]);
        acc[1][0] = MFMA32(af1, __builtin_bit_cast(short8, v0), acc[1][0]);
        acc[1][1] = MFMA32(af1, __builtin_bit_cast(short8, v1), acc[1][1]);
        acc[1][2] = MFMA32(af1, __builtin_bit_cast(short8, v2), acc[1][2]);
        acc[1][3] = MFMA32(af1, __builtin_bit_cast(short8, v3), acc[1][3]);
        __builtin_amdgcn_sched_barrier(0);
        // refill this slot with group (i+4)&15 (wrap re-stages identical bytes)
        const unsigned short* gsrc = gbase + (size_t)((i + 4) & 15) * 2048;
        unsigned short* ld = sbase + (i & 3) * 2048;
#pragma unroll
        for (int c = 0; c < 4; ++c)
            gload_lds16(gsrc + c * 512, ld + c * 512);
    }

    // per-row softmax partial sums (combine hi halves)
    sp0 += __shfl_xor(sp0, 32, 64);
    sp1 += __shfl_xor(sp1, 32, 64);
    if (lane < 32) { sps[wv][l31] = sp0; sps[wv][32 + l31] = sp1; }

    __syncthreads();   // drain outstanding DMAs; staging region reusable as lred

    float (*lred)[64][128] = (float (*)[64][128])smem;   // [4][64][128]

    // ---- 3-stage cross-wave reduction tree ----
    if (wv >= 4) {
#pragma unroll
        for (int r = 0; r < 16; ++r) {
            int crow = (r & 3) + 8 * (r >> 2) + 4 * hi;
#pragma unroll
            for (int s = 0; s < 2; ++s)
#pragma unroll
                for (int c = 0; c < 4; ++c)
                    lred[wv - 4][s * 32 + crow][c * 32 + l31] = acc[s][c][r];
        }
    }
    __syncthreads();
    if (wv < 4) {
#pragma unroll
        for (int r = 0; r < 16; ++r) {
            int crow = (r & 3) + 8 * (r >> 2) + 4 * hi;
#pragma unroll
            for (int s = 0; s < 2; ++s)
#pragma unroll
                for (int c = 0; c < 4; ++c)
                    acc[s][c][r] += lred[wv][s * 32 + crow][c * 32 + l31];
        }
    } else if (wv == 4) {
        float tot = 0.f;
#pragma unroll
        for (int w = 0; w < 8; ++w) tot += sps[w][lane];
        sinv[lane] = 1.0f / tot;
    }
    __syncthreads();
    if (wv == 2 || wv == 3) {
#pragma unroll
        for (int r = 0; r < 16; ++r) {
            int crow = (r & 3) + 8 * (r >> 2) + 4 * hi;
#pragma unroll
            for (int s = 0; s < 2; ++s)
#pragma unroll
                for (int c = 0; c < 4; ++c)
                    lred[wv - 2][s * 32 + crow][c * 32 + l31] = acc[s][c][r];
        }
    }
    __syncthreads();
    if (wv < 2) {
#pragma unroll
        for (int r = 0; r < 16; ++r) {
            int crow = (r & 3) + 8 * (r >> 2) + 4 * hi;
#pragma unroll
            for (int s = 0; s < 2; ++s)
#pragma unroll
                for (int c = 0; c < 4; ++c)
                    acc[s][c][r] += lred[wv][s * 32 + crow][c * 32 + l31];
        }
    }
    __syncthreads();
    if (wv == 1) {
#pragma unroll
        for (int r = 0; r < 16; ++r) {
            int crow = (r & 3) + 8 * (r >> 2) + 4 * hi;
#pragma unroll
            for (int s = 0; s < 2; ++s)
#pragma unroll
                for (int c = 0; c < 4; ++c)
                    lred[0][s * 32 + crow][c * 32 + l31] = acc[s][c][r];
        }
    }
    __syncthreads();
    if (wv == 0) {
        const size_t obase = ((size_t)b * 2048 + (size_t)tile * 64) * 128;
#pragma unroll
        for (int r = 0; r < 16; ++r) {
            int crow = (r & 3) + 8 * (r >> 2) + 4 * hi;
#pragma unroll
            for (int s = 0; s < 2; ++s) {
                int row = s * 32 + crow;
                float iv = sinv[row];
#pragma unroll
                for (int c = 0; c < 4; ++c) {
                    float v = acc[s][c][r] + lred[0][row][c * 32 + l31];
                    out[obase + (size_t)row * 128 + c * 32 + l31] = v * iv;
                }
            }
        }
    }
}

extern "C" void kernel_launch(void* const* d_in, const int* in_sizes, int n_in,
                              void* d_out, int out_size, void* d_ws, size_t ws_size,
                              hipStream_t stream) {
    const float* x = (const float*)d_in[0];
    const float* W = (const float*)d_in[1];
    const float* a = (const float*)d_in[2];
    float* out = (float*)d_out;

    unsigned short* WT2h = (unsigned short*)d_ws;
    unsigned short* WT2l = WT2h + 128 * 128;
    unsigned short* HT2h = WT2l + 128 * 128;
    float* f1l = (float*)(HT2h + (size_t)8 * 128 * 2048);
    float* f2l = f1l + 16384;
    unsigned int* f2mk = (unsigned int*)(f2l + 16384);

    gat_wt<<<8, 256, 0, stream>>>(W, WT2h, WT2l, f2mk);
    gat_h<<<512, 256, 0, stream>>>(x, WT2h, WT2l, a, HT2h, f1l, f2l, f2mk);
    gat_attn<<<256, 512, 0, stream>>>(HT2h, f1l, f2l, f2mk, out);
}

// Round 7
// 39.243 us; speedup vs baseline: 1.0589x; 1.0589x over previous
//
#include <hip/hip_runtime.h>
#include <hip/hip_bf16.h>

typedef __attribute__((ext_vector_type(8))) short short8;
typedef __attribute__((ext_vector_type(8))) unsigned short ushort8;
typedef __attribute__((ext_vector_type(16))) float f32x16;

#define LOG2E 1.4426950408889634f
#define MFMA32(a, b, c) __builtin_amdgcn_mfma_f32_32x32x16_bf16((a), (b), (c), 0, 0, 0)
#define ZERO16 {0.f,0.f,0.f,0.f,0.f,0.f,0.f,0.f,0.f,0.f,0.f,0.f,0.f,0.f,0.f,0.f}

__device__ __forceinline__ unsigned short bfbits(float f) {
    __hip_bfloat16 h = __float2bfloat16(f);
    return __builtin_bit_cast(unsigned short, h);
}
__device__ __forceinline__ float bf2f(unsigned short u) {
    unsigned v = ((unsigned)u) << 16;
    return __builtin_bit_cast(float, v);
}

// ---- kernel 1: h = x@W via MFMA (hi/lo, W preloaded to regs from raw W);
//      writes HT2[j/16][d][j%16] bf16, f1l, f2l, per-batch f2 max (atomicMax) ----
__global__ __launch_bounds__(256) void gat_h(const float* __restrict__ x,
                                             const float* __restrict__ W,
                                             const float* __restrict__ a,
                                             unsigned short* __restrict__ HT2h,
                                             float* __restrict__ f1l,
                                             float* __restrict__ f2l,
                                             unsigned int* __restrict__ f2mk) {
    __shared__ unsigned short xs_h[32][132];
    __shared__ unsigned short xs_l[32][132];
    __shared__ float hs[32][130];
    __shared__ float red[2][32][8];
    const int tid = threadIdx.x;
    const int lane = tid & 63;
    const int wv = tid >> 6;          // 4 waves, one 32-col tile each
    const int l31 = lane & 31;
    const int hi = lane >> 5;
    const int t0 = blockIdx.x * 32;   // global row (8*2048 rows total)
    const int c0 = wv * 32;

    // preload this wave's W fragments (fp32) -> registers
    float wf[64];
#pragma unroll
    for (int kk8 = 0; kk8 < 8; ++kk8)
#pragma unroll
        for (int q = 0; q < 8; ++q)
            wf[kk8 * 8 + q] = W[(kk8 * 16 + 8 * hi + q) * 128 + c0 + l31];

    // stage x tile coalesced, convert to bf16 hi/lo once
#pragma unroll
    for (int r8 = 0; r8 < 4; ++r8) {
        int row = r8 * 8 + (tid >> 5);
        int c4 = (tid & 31) * 4;
        float4 v = *(const float4*)(x + (size_t)(t0 + row) * 128 + c4);
        float f[4] = {v.x, v.y, v.z, v.w};
#pragma unroll
        for (int q = 0; q < 4; ++q) {
            unsigned short hb = bfbits(f[q]);
            xs_h[row][c4 + q] = hb;
            xs_l[row][c4 + q] = bfbits(f[q] - bf2f(hb));
        }
    }

    // convert W fragments to bf16 hi/lo in registers
    short8 wh[8], wl[8];
#pragma unroll
    for (int kk8 = 0; kk8 < 8; ++kk8)
#pragma unroll
        for (int q = 0; q < 8; ++q) {
            float f = wf[kk8 * 8 + q];
            unsigned short hb = bfbits(f);
            wh[kk8][q] = (short)hb;
            wl[kk8][q] = (short)bfbits(f - bf2f(hb));
        }
    __syncthreads();

    f32x16 p0 = ZERO16, p1 = ZERO16, p2 = ZERO16;  // xhi*Whi, xlo*Whi, xhi*Wlo
#pragma unroll
    for (int kk8 = 0; kk8 < 8; ++kk8) {
        short8 ah = *(const short8*)&xs_h[l31][kk8 * 16 + 8 * hi];
        short8 al = *(const short8*)&xs_l[l31][kk8 * 16 + 8 * hi];
        p0 = MFMA32(ah, wh[kk8], p0);
        p1 = MFMA32(al, wh[kk8], p1);
        p2 = MFMA32(ah, wl[kk8], p2);
    }
#pragma unroll
    for (int r = 0; r < 16; ++r) {
        int crow = (r & 3) + 8 * (r >> 2) + 4 * hi;
        hs[crow][c0 + l31] = p0[r] + p1[r] + p2[r];
    }
    __syncthreads();
    // HT2 writes: thread owns one d, 16 consecutive j's -> contiguous 32B
    {
        const int d = tid & 127, half = tid >> 7;
        ushort8 h0, h1;
#pragma unroll
        for (int j = 0; j < 8; ++j) h0[j] = bfbits(hs[half * 16 + j][d]);
#pragma unroll
        for (int j = 0; j < 8; ++j) h1[j] = bfbits(hs[half * 16 + 8 + j][d]);
        const int b = t0 >> 11;
        const int tloc = t0 & 2047;
        size_t base = (size_t)b * 262144 + (size_t)(tloc / 16 + half) * 2048 + d * 16;
        *(ushort8*)(HT2h + base) = h0;
        *(ushort8*)(HT2h + base + 8) = h1;
    }
    // f1 = h@a1, f2 = h@a2 (pre-scaled by log2e)
    {
        const int r = tid & 31, seg = tid >> 5;
        float s1 = 0.f, s2 = 0.f;
#pragma unroll
        for (int i = 0; i < 16; ++i) {
            float hv = hs[r][seg * 16 + i];
            s1 += hv * a[seg * 16 + i];
            s2 += hv * a[128 + seg * 16 + i];
        }
        red[0][r][seg] = s1;
        red[1][r][seg] = s2;
    }
    __syncthreads();
    if (tid < 32) {
        float s1 = 0.f, s2 = 0.f;
#pragma unroll
        for (int g = 0; g < 8; ++g) { s1 += red[0][tid][g]; s2 += red[1][tid][g]; }
        f1l[t0 + tid] = s1 * LOG2E;
        float f2v = s2 * LOG2E;
        f2l[t0 + tid] = f2v;
        // block-level f2 max -> one atomicMax per block (sign-flipped uint key)
        float m = f2v;
#pragma unroll
        for (int o = 1; o < 32; o <<= 1) m = fmaxf(m, __shfl_xor(m, o, 32));
        if (tid == 0) {
            unsigned int bits = __builtin_bit_cast(unsigned int, m);
            unsigned int key = (bits & 0x80000000u) ? ~bits : (bits | 0x80000000u);
            atomicMax(f2mk + (t0 >> 11), key);
        }
    }
}

// ---- kernel 2: fused P-gen + softmax-denominator + P@H -------------------------
// grid 512 = 8 batches x 64 tiles of 32 rows; 512 threads = 8 waves (8-way j-split).
// acc = 64 VGPR, LDS ~73 KB -> 2 blocks/CU co-resident = 4 waves/SIMD.
__global__ __launch_bounds__(512, 4) void gat_attn(const unsigned short* __restrict__ HT2h,
                                                   const float* __restrict__ f1l,
                                                   const float* __restrict__ f2l,
                                                   const unsigned int* __restrict__ f2mk,
                                                   float* __restrict__ out) {
    __shared__ float lred[4][32][128];   // 64 KB partials
    __shared__ float f2s[2048];          // 8 KB
    __shared__ float sps[8][32];
    __shared__ float sinv[32];
    const int bid = blockIdx.x;
    const int b = bid & 7;          // batch == XCD for L2 locality
    const int tile = bid >> 3;      // 0..63, 32 rows each
    const int tid = threadIdx.x;
    const int lane = tid & 63;
    const int wv = tid >> 6;        // 0..7 = j-chunk
    const int l31 = lane & 31;
    const int hi = lane >> 5;
    const int koff = hi * 8;

    // stage f2 batch slice into LDS (one coalesced burst)
    *(float4*)(f2s + tid * 4) = *(const float4*)(f2l + b * 2048 + tid * 4);

    const unsigned int kk = f2mk[b];
    const unsigned int mbits = (kk & 0x80000000u) ? (kk & 0x7fffffffu) : ~kk;
    const float fm = __builtin_bit_cast(float, mbits);

    const float f1m = f1l[b * 2048 + tile * 32 + l31];
    const float tm = f1m + fm;
    const float ml = fmaxf(tm, 0.2f * tm);    // exact row max (lrelu monotonic)
    const float A0 = f1m - ml, B0 = 0.2f * f1m - ml;

    const int jloc = wv * 256;
    const unsigned short* gbase = HT2h + (size_t)b * 262144
                                + (size_t)(jloc >> 4) * 2048 + l31 * 16 + koff;

    f32x16 acc0 = ZERO16, acc1 = ZERO16, acc2 = ZERO16, acc3 = ZERO16;
    float sp = 0.f;

    // depth-1 prefetch of H B-fragments (contiguous 1KB per wave instruction)
    uint4 X0 = *(const uint4*)(gbase);
    uint4 X1 = *(const uint4*)(gbase + 512);
    uint4 X2 = *(const uint4*)(gbase + 1024);
    uint4 X3 = *(const uint4*)(gbase + 1536);

    __syncthreads();   // f2s ready

    for (int i = 0; i < 16; ++i) {
        float4 fa = *(const float4*)(f2s + jloc + i * 16 + koff);
        float4 fb = *(const float4*)(f2s + jloc + i * 16 + koff + 4);
        // prefetch next group
        const unsigned short* pn = gbase + (size_t)((i + 1) & 15) * 2048;
        uint4 N0 = *(const uint4*)(pn);
        uint4 N1 = *(const uint4*)(pn + 512);
        uint4 N2 = *(const uint4*)(pn + 1024);
        uint4 N3 = *(const uint4*)(pn + 1536);

        float fv[8] = {fa.x, fa.y, fa.z, fa.w, fb.x, fb.y, fb.z, fb.w};
        short8 af;
#pragma unroll
        for (int q = 0; q < 8; ++q) {
            float g = 0.2f * fv[q];
            float p = __builtin_amdgcn_exp2f(fmaxf(A0 + fv[q], B0 + g));
            sp += p;
            af[q] = (short)bfbits(p);
        }
        acc0 = MFMA32(af, __builtin_bit_cast(short8, X0), acc0);
        acc1 = MFMA32(af, __builtin_bit_cast(short8, X1), acc1);
        acc2 = MFMA32(af, __builtin_bit_cast(short8, X2), acc2);
        acc3 = MFMA32(af, __builtin_bit_cast(short8, X3), acc3);
        X0 = N0; X1 = N1; X2 = N2; X3 = N3;
    }

    sp += __shfl_xor(sp, 32, 64);
    if (lane < 32) sps[wv][l31] = sp;

    // ---- 3-stage cross-wave reduction tree ----
    if (wv >= 4) {
#pragma unroll
        for (int r = 0; r < 16; ++r) {
            int crow = (r & 3) + 8 * (r >> 2) + 4 * hi;
            lred[wv - 4][crow][l31] = acc0[r];
            lred[wv - 4][crow][32 + l31] = acc1[r];
            lred[wv - 4][crow][64 + l31] = acc2[r];
            lred[wv - 4][crow][96 + l31] = acc3[r];
        }
    }
    __syncthreads();
    if (wv < 4) {
#pragma unroll
        for (int r = 0; r < 16; ++r) {
            int crow = (r & 3) + 8 * (r >> 2) + 4 * hi;
            acc0[r] += lred[wv][crow][l31];
            acc1[r] += lred[wv][crow][32 + l31];
            acc2[r] += lred[wv][crow][64 + l31];
            acc3[r] += lred[wv][crow][96 + l31];
        }
    } else if (wv == 4) {
        if (lane < 32) {
            float tot = 0.f;
#pragma unroll
            for (int w = 0; w < 8; ++w) tot += sps[w][l31];
            sinv[l31] = 1.0f / tot;
        }
    }
    __syncthreads();
    if (wv == 2 || wv == 3) {
#pragma unroll
        for (int r = 0; r < 16; ++r) {
            int crow = (r & 3) + 8 * (r >> 2) + 4 * hi;
            lred[wv - 2][crow][l31] = acc0[r];
            lred[wv - 2][crow][32 + l31] = acc1[r];
            lred[wv - 2][crow][64 + l31] = acc2[r];
            lred[wv - 2][crow][96 + l31] = acc3[r];
        }
    }
    __syncthreads();
    if (wv < 2) {
#pragma unroll
        for (int r = 0; r < 16; ++r) {
            int crow = (r & 3) + 8 * (r >> 2) + 4 * hi;
            acc0[r] += lred[wv][crow][l31];
            acc1[r] += lred[wv][crow][32 + l31];
            acc2[r] += lred[wv][crow][64 + l31];
            acc3[r] += lred[wv][crow][96 + l31];
        }
    }
    __syncthreads();
    if (wv == 1) {
#pragma unroll
        for (int r = 0; r < 16; ++r) {
            int crow = (r & 3) + 8 * (r >> 2) + 4 * hi;
            lred[0][crow][l31] = acc0[r];
            lred[0][crow][32 + l31] = acc1[r];
            lred[0][crow][64 + l31] = acc2[r];
            lred[0][crow][96 + l31] = acc3[r];
        }
    }
    __syncthreads();
    if (wv == 0) {
        const size_t obase = ((size_t)b * 2048 + (size_t)tile * 32) * 128;
#pragma unroll
        for (int r = 0; r < 16; ++r) {
            int crow = (r & 3) + 8 * (r >> 2) + 4 * hi;
            float iv = sinv[crow];
            out[obase + (size_t)crow * 128 + l31]       = (acc0[r] + lred[0][crow][l31]) * iv;
            out[obase + (size_t)crow * 128 + 32 + l31]  = (acc1[r] + lred[0][crow][32 + l31]) * iv;
            out[obase + (size_t)crow * 128 + 64 + l31]  = (acc2[r] + lred[0][crow][64 + l31]) * iv;
            out[obase + (size_t)crow * 128 + 96 + l31]  = (acc3[r] + lred[0][crow][96 + l31]) * iv;
        }
    }
}

extern "C" void kernel_launch(void* const* d_in, const int* in_sizes, int n_in,
                              void* d_out, int out_size, void* d_ws, size_t ws_size,
                              hipStream_t stream) {
    const float* x = (const float*)d_in[0];
    const float* W = (const float*)d_in[1];
    const float* a = (const float*)d_in[2];
    float* out = (float*)d_out;

    unsigned short* HT2h = (unsigned short*)d_ws;
    float* f1l = (float*)(HT2h + (size_t)8 * 128 * 2048);
    float* f2l = f1l + 16384;
    unsigned int* f2mk = (unsigned int*)(f2l + 16384);

    hipMemsetAsync(f2mk, 0, 8 * sizeof(unsigned int), stream);
    gat_h<<<512, 256, 0, stream>>>(x, W, a, HT2h, f1l, f2l, f2mk);
    gat_attn<<<512, 512, 0, stream>>>(HT2h, f1l, f2l, f2mk, out);
}